// Round 7
// baseline (379.532 us; speedup 1.0000x reference)
//
#include <hip/hip_runtime.h>
#include <hip/hip_bf16.h>
#include <math.h>

#define EMBED 1024
#define HEADS 16
#define DH    64
#define BATCH 2
#define SEQ   2048

typedef __attribute__((ext_vector_type(8))) short bf16x8;
typedef __attribute__((ext_vector_type(4))) short bf16x4;
typedef __attribute__((ext_vector_type(4))) float f32x4;
typedef unsigned long long u64;

#define QSCALE 0.1803368801111244f   // 0.125 * log2(e): exp(s/8) == exp2(s*QSCALE)

static __device__ __forceinline__ unsigned short f2bf(float x) {
    unsigned u = __builtin_bit_cast(unsigned, x);
    return (unsigned short)((u + 0x7fffu + ((u >> 16) & 1u)) >> 16);
}
static __device__ __forceinline__ unsigned pk2bf(float a, float b) {
    union { __hip_bfloat162 h2; unsigned u; } c;
    c.h2 = __float22bfloat162_rn(make_float2(a, b));
    return c.u;
}

// ---------------------------------------------------------------------------
// Kernel 1: QKV projection via MFMA. X viewed as [M=B*S*H][64]; Y = X W^T + b,
// written bf16 to [B,H,S,DH]. Q output is pre-scaled by QSCALE so attention
// can use raw exp2. grid = (1024, 3), block = 256.
// ---------------------------------------------------------------------------
__global__ __launch_bounds__(256) void proj_mfma(
    const float* __restrict__ q, const float* __restrict__ k, const float* __restrict__ v,
    const float* __restrict__ Wq, const float* __restrict__ bq,
    const float* __restrict__ Wk, const float* __restrict__ bk,
    const float* __restrict__ Wv, const float* __restrict__ bv,
    unsigned short* __restrict__ qh, unsigned short* __restrict__ kh,
    unsigned short* __restrict__ vh)
{
    const int blk = blockIdx.x;           // 0..1023
    const int which = blockIdx.y;
    const float* x; const float* W; const float* bias; unsigned short* out;
    if (which == 0)      { x = q; W = Wq; bias = bq; out = qh; }
    else if (which == 1) { x = k; W = Wk; bias = bk; out = kh; }
    else                 { x = v; W = Wv; bias = bv; out = vh; }
    const float oscale = (which == 0) ? QSCALE : 1.0f;

    __shared__ unsigned short Xs[64 * 72];
    __shared__ unsigned short Ws[64 * 72];

    const int t  = threadIdx.x;
    const int sr = t >> 2, sp = t & 3;

    {
        const float* xsrc = x + ((size_t)blk * 64 + sr) * 64 + sp * 16;
        unsigned o32[8];
#pragma unroll
        for (int u4 = 0; u4 < 4; ++u4) {
            float4 a = ((const float4*)xsrc)[u4];
            o32[u4 * 2 + 0] = pk2bf(a.x, a.y);
            o32[u4 * 2 + 1] = pk2bf(a.z, a.w);
        }
        *(uint4*)&Xs[sr * 72 + sp * 16]     = *(uint4*)&o32[0];
        *(uint4*)&Xs[sr * 72 + sp * 16 + 8] = *(uint4*)&o32[4];
        const float* wsrc = W + (size_t)sr * 64 + sp * 16;
#pragma unroll
        for (int u4 = 0; u4 < 4; ++u4) {
            float4 a = ((const float4*)wsrc)[u4];
            o32[u4 * 2 + 0] = pk2bf(a.x, a.y);
            o32[u4 * 2 + 1] = pk2bf(a.z, a.w);
        }
        *(uint4*)&Ws[sr * 72 + sp * 16]     = *(uint4*)&o32[0];
        *(uint4*)&Ws[sr * 72 + sp * 16 + 8] = *(uint4*)&o32[4];
    }
    __syncthreads();

    const int w    = t >> 6;
    const int lane = t & 63;
    const int l15  = lane & 15;
    const int quad = lane >> 4;

    bf16x8 af0 = *(const bf16x8*)&Xs[(w * 16 + l15) * 72 + quad * 8];
    bf16x8 af1 = *(const bf16x8*)&Xs[(w * 16 + l15) * 72 + 32 + quad * 8];

    f32x4 acc[4];
#pragma unroll
    for (int nt = 0; nt < 4; ++nt) {
        bf16x8 bf0 = *(const bf16x8*)&Ws[(nt * 16 + l15) * 72 + quad * 8];
        bf16x8 bf1 = *(const bf16x8*)&Ws[(nt * 16 + l15) * 72 + 32 + quad * 8];
        f32x4 a = {0, 0, 0, 0};
        a = __builtin_amdgcn_mfma_f32_16x16x32_bf16(af0, bf0, a, 0, 0, 0);
        a = __builtin_amdgcn_mfma_f32_16x16x32_bf16(af1, bf1, a, 0, 0, 0);
        acc[nt] = a;
    }

    const int bsidx = blk * 4 + w;
    const int b = bsidx >> 11, s = bsidx & 2047;
#pragma unroll
    for (int nt = 0; nt < 4; ++nt) {
        const int d = nt * 16 + l15;
        const float bb = bias[d];
#pragma unroll
        for (int r = 0; r < 4; ++r) {
            const int h = quad * 4 + r;
            out[(((size_t)b * HEADS + h) * SEQ + s) * DH + d] =
                f2bf((acc[nt][r] + bb) * oscale);
        }
    }
}

// ---------------------------------------------------------------------------
// Kernel 2 (fused prep): vtrans (bid<1024) | maskpack (<1536) | wcvt (rest)
// ---------------------------------------------------------------------------
__global__ __launch_bounds__(256) void prep_kernel(
    const unsigned short* __restrict__ vh, unsigned short* __restrict__ vt,
    const int* __restrict__ mask, u64* __restrict__ bits,
    const float* __restrict__ Wo, unsigned short* __restrict__ Wob)
{
    __shared__ unsigned short Tt[64 * 72];
    const int bid = blockIdx.x;
    const int t   = threadIdx.x;

    if (bid < 1024) {                     // ---- V transpose ----
        const int st = bid & 31;
        const int bh = bid >> 5;
        const int r = t >> 2, p = t & 3;
        const unsigned short* src = vh + ((size_t)bh * SEQ + st * 64 + r) * DH + p * 16;
        *(uint4*)&Tt[r * 72 + p * 16]     = *(const uint4*)src;
        *(uint4*)&Tt[r * 72 + p * 16 + 8] = *(const uint4*)(src + 8);
        __syncthreads();
        union { unsigned short u[16]; uint4 v[2]; } o;
#pragma unroll
        for (int u = 0; u < 16; ++u) o.u[u] = Tt[(p * 16 + u) * 72 + r];
        unsigned short* dst = vt + ((size_t)bh * DH + r) * SEQ + st * 64 + p * 16;
        *(uint4*)dst       = o.v[0];
        *(uint4*)(dst + 8) = o.v[1];
    } else if (bid < 1536) {              // ---- mask -> bitmask ----
        const int idx = (bid - 1024) * 256 + t;
        const int4* src = (const int4*)(mask + (size_t)idx * 64);
        u64 w = 0;
#pragma unroll
        for (int u = 0; u < 16; ++u) {
            int4 m = src[u];
            u64 nib = (m.x != 0 ? 1ull : 0) | (m.y != 0 ? 2ull : 0) |
                      (m.z != 0 ? 4ull : 0) | (m.w != 0 ? 8ull : 0);
            w |= nib << (u * 4);
        }
        bits[idx] = w;
    } else {                              // ---- Wo fp32 -> bf16 ----
        const int i = ((bid - 1536) * 256 + t) * 8;
        float4 a = ((const float4*)(Wo + i))[0];
        float4 b = ((const float4*)(Wo + i))[1];
        unsigned o32[4] = {pk2bf(a.x, a.y), pk2bf(a.z, a.w),
                           pk2bf(b.x, b.y), pk2bf(b.z, b.w)};
        *(uint4*)(Wob + i) = *(uint4*)o32;
    }
}

// ---------------------------------------------------------------------------
// Kernel 3: MFMA flash attention. Transposed scores (P stays in registers as
// the K=16 MFMA A-fragment), MFMA row-sums (ones-vector B), split-K in block.
// block = 256 (4 waves): waves 0-1 = K half 0, waves 2-3 = K half 1; each wave
// owns 32 of the block's 64 Q rows. grid = flat 1024 (4 blocks/CU);
// bh = bid & 31 keeps each bh's K/V on one XCD.
// ---------------------------------------------------------------------------
__global__ __launch_bounds__(256, 4) void attn_kernel(
    const unsigned short* __restrict__ qh, const unsigned short* __restrict__ kh,
    const unsigned short* __restrict__ vt, const u64* __restrict__ mbits,
    unsigned short* __restrict__ ctx)
{
    const int bid = blockIdx.x;
    const int bh  = bid & 31;
    const int q0  = (bid >> 5) * 64;
    const int b   = bh >> 4;

    __shared__ uint4 smem4[2304];         // 36864 B: 2 halves x (Kt+Vt); epilogue reuse
    unsigned short* smem = (unsigned short*)smem4;

    const int t    = threadIdx.x;
    const int hh   = t >> 7;              // compute K-half (waves 0-1 / 2-3)
    const int w2   = (t >> 6) & 1;        // wave within half
    const int lane = t & 63;
    const int l15  = lane & 15;
    const int quad = lane >> 4;

    unsigned short* KtH = smem + hh * 9216;
    unsigned short* VtH = KtH + 4608;

    // staging mapping: thread stages 64 B of K and 64 B of V for half (t>>7)
    const int t3 = t & 127;
    const int sr = t3 >> 1, sp = t3 & 1;  // row 0..63, col-block of 32
    unsigned short* Kdst = smem + hh * 9216 + sr * 72 + sp * 32;
    unsigned short* Vdst = Kdst + 4608;

    // Q fragments (32 rows per wave, resident for the whole loop)
    bf16x8 qf[2][2];
#pragma unroll
    for (int g = 0; g < 2; ++g) {
        const unsigned short* qb =
            qh + ((size_t)bh * SEQ + q0 + w2 * 32 + g * 16 + l15) * DH + quad * 8;
        qf[g][0] = *(const bf16x8*)qb;
        qf[g][1] = *(const bf16x8*)(qb + 32);
    }

    f32x4 O[2][4];
#pragma unroll
    for (int g = 0; g < 2; ++g)
#pragma unroll
        for (int dt = 0; dt < 4; ++dt) O[g][dt] = f32x4{0, 0, 0, 0};
    f32x4 Osum[2] = {f32x4{0, 0, 0, 0}, f32x4{0, 0, 0, 0}};
    const bf16x4 ones = {(short)0x3F80, (short)0x3F80, (short)0x3F80, (short)0x3F80};

    const unsigned short* kbase = kh + (size_t)bh * SEQ * DH + (size_t)hh * 1024 * DH;
    const unsigned short* vbase = vt + (size_t)bh * DH * SEQ + hh * 1024;
    const u64* mrow0 = mbits + ((size_t)b * SEQ + q0 + w2 * 32 + l15) * (SEQ / 64) + hh * 16;
    const u64* mrow1 = mrow0 + 16 * (SEQ / 64);

    // prefetch tile 0
    uint4 pk[4], pv[4];
    u64 pm0, pm1;
    {
        const unsigned short* ks = kbase + (size_t)sr * DH + sp * 32;
        const unsigned short* vs = vbase + (size_t)sr * SEQ + sp * 32;
#pragma unroll
        for (int u = 0; u < 4; ++u) {
            pk[u] = *(const uint4*)(ks + u * 8);
            pv[u] = *(const uint4*)(vs + u * 8);
        }
        pm0 = mrow0[0]; pm1 = mrow1[0];
    }

    for (int kt = 0; kt < 16; ++kt) {
        __syncthreads();                  // previous tile's readers done
#pragma unroll
        for (int u = 0; u < 4; ++u) {
            *(uint4*)(Kdst + u * 8) = pk[u];
            *(uint4*)(Vdst + u * 8) = pv[u];
        }
        const u64 mb0 = pm0, mb1 = pm1;
        if (kt < 15) {                    // prefetch next tile during compute
            const unsigned short* ks = kbase + (size_t)((kt + 1) * 64 + sr) * DH + sp * 32;
            const unsigned short* vs = vbase + (size_t)sr * SEQ + (kt + 1) * 64 + sp * 32;
#pragma unroll
            for (int u = 0; u < 4; ++u) {
                pk[u] = *(const uint4*)(ks + u * 8);
                pv[u] = *(const uint4*)(vs + u * 8);
            }
            pm0 = mrow0[kt + 1]; pm1 = mrow1[kt + 1];
        }
        __syncthreads();                  // tile staged

        // ---- S^T tiles + masked exp2; P stays in registers ----
        bf16x4 p[2][4];
#pragma unroll
        for (int st = 0; st < 4; ++st) {
            bf16x8 kf0 = *(const bf16x8*)&KtH[(st * 16 + l15) * 72 + quad * 8];
            bf16x8 kf1 = *(const bf16x8*)&KtH[(st * 16 + l15) * 72 + 32 + quad * 8];
#pragma unroll
            for (int g = 0; g < 2; ++g) {
                f32x4 sa = {0, 0, 0, 0};
                sa = __builtin_amdgcn_mfma_f32_16x16x32_bf16(kf0, qf[g][0], sa, 0, 0, 0);
                sa = __builtin_amdgcn_mfma_f32_16x16x32_bf16(kf1, qf[g][1], sa, 0, 0, 0);
                const unsigned nib = (unsigned)((g ? mb1 : mb0) >> (st * 16 + quad * 4)) & 0xFu;
                float p0 = (nib & 1u) ? exp2f(sa[0]) : 0.f;
                float p1 = (nib & 2u) ? exp2f(sa[1]) : 0.f;
                float p2 = (nib & 4u) ? exp2f(sa[2]) : 0.f;
                float p3 = (nib & 8u) ? exp2f(sa[3]) : 0.f;
                union { unsigned u2[2]; bf16x4 v; } pu;
                pu.u2[0] = pk2bf(p0, p1);
                pu.u2[1] = pk2bf(p2, p3);
                p[g][st] = pu.v;
                // MFMA row-sum: C[m=quad*4+r][*] = sum_j P[m][j]
                Osum[g] = __builtin_amdgcn_mfma_f32_16x16x16bf16_1k(p[g][st], ones, Osum[g], 0, 0, 0);
            }
        }

        // ---- PV: O[g][dt] += P * V ----
#pragma unroll
        for (int dt = 0; dt < 4; ++dt) {
#pragma unroll
            for (int st = 0; st < 4; ++st) {
                bf16x4 vb = *(const bf16x4*)&VtH[(dt * 16 + l15) * 72 + st * 16 + quad * 4];
                O[0][dt] = __builtin_amdgcn_mfma_f32_16x16x16bf16_1k(p[0][st], vb, O[0][dt], 0, 0, 0);
                O[1][dt] = __builtin_amdgcn_mfma_f32_16x16x16bf16_1k(p[1][st], vb, O[1][dt], 0, 0, 0);
            }
        }
    }

    // ---- merge halves through LDS (fixed-max softmax => pure add) ----
    float* Obuf = (float*)smem4;          // [64][66] f32
    float* Ls   = ((float*)smem4) + 64 * 66;  // [64]

    __syncthreads();                      // all K/V reads complete
    if (hh == 0) {
#pragma unroll
        for (int g = 0; g < 2; ++g) {
#pragma unroll
            for (int dt = 0; dt < 4; ++dt)
#pragma unroll
                for (int r = 0; r < 4; ++r)
                    Obuf[(w2 * 32 + g * 16 + quad * 4 + r) * 66 + dt * 16 + l15] = O[g][dt][r];
            if (l15 == 0) {
#pragma unroll
                for (int r = 0; r < 4; ++r)
                    Ls[w2 * 32 + g * 16 + quad * 4 + r] = Osum[g][r];
            }
        }
    }
    __syncthreads();
    if (hh == 1) {
#pragma unroll
        for (int g = 0; g < 2; ++g) {
            float invr[4];
#pragma unroll
            for (int r = 0; r < 4; ++r) {
                const int row = w2 * 32 + g * 16 + quad * 4 + r;
                invr[r] = 1.0f / (Osum[g][r] + Ls[row]);
            }
#pragma unroll
            for (int r = 0; r < 4; ++r) {
                const int row = w2 * 32 + g * 16 + quad * 4 + r;
                unsigned short* dst = ctx + ((size_t)bh * SEQ + q0 + row) * DH + l15;
#pragma unroll
                for (int dt = 0; dt < 4; ++dt) {
                    const float val = O[g][dt][r] + Obuf[row * 66 + dt * 16 + l15];
                    dst[dt * 16] = f2bf(val * invr[r]);
                }
            }
        }
    }
}

// ---------------------------------------------------------------------------
// Kernel 4: output projection via MFMA (verified R3/R5/R6).
// ---------------------------------------------------------------------------
__global__ __launch_bounds__(256) void outproj_mfma(
    const unsigned short* __restrict__ ctx, const unsigned short* __restrict__ Wob,
    const float* __restrict__ bo, float* __restrict__ out)
{
    const int n0 = blockIdx.x * 64;
    const int m0 = blockIdx.y * 64;
    const int b  = m0 / SEQ;
    const int s0 = m0 % SEQ;

    __shared__ unsigned short At[64 * 72];
    __shared__ unsigned short Wt[64 * 72];

    const int t    = threadIdx.x;
    const int w    = t >> 6;
    const int lane = t & 63;
    const int l15  = lane & 15;
    const int quad = lane >> 4;
    const int sr = t >> 2, sp = t & 3;

    f32x4 acc[4] = {f32x4{0,0,0,0}, f32x4{0,0,0,0}, f32x4{0,0,0,0}, f32x4{0,0,0,0}};

    for (int kt = 0; kt < HEADS; ++kt) {
        __syncthreads();
        {
            const unsigned short* as =
                ctx + (((size_t)b * HEADS + kt) * SEQ + s0 + sr) * DH + sp * 16;
            *(uint4*)&At[sr * 72 + sp * 16]     = *(const uint4*)as;
            *(uint4*)&At[sr * 72 + sp * 16 + 8] = *(const uint4*)(as + 8);
            const unsigned short* wsrc =
                Wob + (size_t)(n0 + sr) * EMBED + kt * 64 + sp * 16;
            *(uint4*)&Wt[sr * 72 + sp * 16]     = *(const uint4*)wsrc;
            *(uint4*)&Wt[sr * 72 + sp * 16 + 8] = *(const uint4*)(wsrc + 8);
        }
        __syncthreads();

        bf16x8 bf0 = *(const bf16x8*)&Wt[(w * 16 + l15) * 72 + quad * 8];
        bf16x8 bf1 = *(const bf16x8*)&Wt[(w * 16 + l15) * 72 + 32 + quad * 8];
#pragma unroll
        for (int mt = 0; mt < 4; ++mt) {
            bf16x8 af0 = *(const bf16x8*)&At[(mt * 16 + l15) * 72 + quad * 8];
            bf16x8 af1 = *(const bf16x8*)&At[(mt * 16 + l15) * 72 + 32 + quad * 8];
            acc[mt] = __builtin_amdgcn_mfma_f32_16x16x32_bf16(af0, bf0, acc[mt], 0, 0, 0);
            acc[mt] = __builtin_amdgcn_mfma_f32_16x16x32_bf16(af1, bf1, acc[mt], 0, 0, 0);
        }
    }

    const float bv = bo[n0 + w * 16 + l15];
#pragma unroll
    for (int mt = 0; mt < 4; ++mt) {
#pragma unroll
        for (int r = 0; r < 4; ++r) {
            out[(size_t)(m0 + mt * 16 + quad * 4 + r) * EMBED + n0 + w * 16 + l15] =
                acc[mt][r] + bv;
        }
    }
}

// ---------------------------------------------------------------------------
extern "C" void kernel_launch(void* const* d_in, const int* in_sizes, int n_in,
                              void* d_out, int out_size, void* d_ws, size_t ws_size,
                              hipStream_t stream) {
    const float* k    = (const float*)d_in[0];
    const float* q    = (const float*)d_in[1];
    const float* v    = (const float*)d_in[2];
    const int*   mask = (const int*)  d_in[3];
    const float* Wk   = (const float*)d_in[4];
    const float* bk   = (const float*)d_in[5];
    const float* Wq   = (const float*)d_in[6];
    const float* bq   = (const float*)d_in[7];
    const float* Wv   = (const float*)d_in[8];
    const float* bv   = (const float*)d_in[9];
    const float* Wo   = (const float*)d_in[10];
    const float* bo   = (const float*)d_in[11];
    float* out = (float*)d_out;

    const size_t TEN = (size_t)BATCH * HEADS * SEQ * DH;   // 4,194,304 elems
    unsigned short* qh_bf = (unsigned short*)d_ws;         // 8 MB
    unsigned short* kh_bf = qh_bf + TEN;                   // 8 MB
    unsigned short* vh_bf = kh_bf + TEN;                   // 8 MB
    unsigned short* vt_bf = vh_bf + TEN;                   // 8 MB
    unsigned short* ctxb  = vt_bf + TEN;                   // 8 MB
    unsigned short* Wob   = ctxb + TEN;                    // 2 MB
    u64*            mbits = (u64*)(Wob + EMBED * EMBED);   // 1 MB  (43 MB total)

    proj_mfma<<<dim3(BATCH * SEQ * HEADS / 64, 3), 256, 0, stream>>>(
        q, k, v, Wq, bq, Wk, bk, Wv, bv, qh_bf, kh_bf, vh_bf);
    prep_kernel<<<dim3(2048), 256, 0, stream>>>(
        vh_bf, vt_bf, mask, mbits, Wo, Wob);
    attn_kernel<<<dim3((SEQ / 64) * BATCH * HEADS), 256, 0, stream>>>(
        qh_bf, kh_bf, vt_bf, mbits, ctxb);
    outproj_mfma<<<dim3(EMBED / 64, BATCH * SEQ / 64), 256, 0, stream>>>(
        ctxb, Wob, bo, out);
}

// Round 8
// 249.513 us; speedup vs baseline: 1.5211x; 1.5211x over previous
//
#include <hip/hip_runtime.h>
#include <hip/hip_bf16.h>
#include <math.h>

#define EMBED 1024
#define HEADS 16
#define DH    64
#define BATCH 2
#define SEQ   2048

typedef __attribute__((ext_vector_type(8))) short bf16x8;
typedef __attribute__((ext_vector_type(4))) short bf16x4;
typedef __attribute__((ext_vector_type(4))) float f32x4;
typedef unsigned long long u64;

#define QSCALE 0.1803368801111244f   // 0.125 * log2(e): exp(s/8) == exp2(s*QSCALE)

static __device__ __forceinline__ unsigned short f2bf(float x) {
    unsigned u = __builtin_bit_cast(unsigned, x);
    return (unsigned short)((u + 0x7fffu + ((u >> 16) & 1u)) >> 16);
}
static __device__ __forceinline__ unsigned pk2bf(float a, float b) {
    union { __hip_bfloat162 h2; unsigned u; } c;
    c.h2 = __float22bfloat162_rn(make_float2(a, b));
    return c.u;
}
// async global->LDS DMA, 16 B per lane; LDS dest = wave-uniform base + lane*16
static __device__ __forceinline__ void gl_lds16(const void* g, void* l) {
    __builtin_amdgcn_global_load_lds(
        (const __attribute__((address_space(1))) void*)g,
        (__attribute__((address_space(3))) void*)l, 16, 0, 0);
}

// ---------------------------------------------------------------------------
// Kernel 1: QKV projection via MFMA. X viewed as [M=B*S*H][64]; Y = X W^T + b,
// written bf16 to [B,H,S,DH]. Q output pre-scaled by QSCALE (exp2 softmax).
// grid = (1024, 3), block = 256.
// ---------------------------------------------------------------------------
__global__ __launch_bounds__(256) void proj_mfma(
    const float* __restrict__ q, const float* __restrict__ k, const float* __restrict__ v,
    const float* __restrict__ Wq, const float* __restrict__ bq,
    const float* __restrict__ Wk, const float* __restrict__ bk,
    const float* __restrict__ Wv, const float* __restrict__ bv,
    unsigned short* __restrict__ qh, unsigned short* __restrict__ kh,
    unsigned short* __restrict__ vh)
{
    const int blk = blockIdx.x;
    const int which = blockIdx.y;
    const float* x; const float* W; const float* bias; unsigned short* out;
    if (which == 0)      { x = q; W = Wq; bias = bq; out = qh; }
    else if (which == 1) { x = k; W = Wk; bias = bk; out = kh; }
    else                 { x = v; W = Wv; bias = bv; out = vh; }
    const float oscale = (which == 0) ? QSCALE : 1.0f;

    __shared__ unsigned short Xs[64 * 72];
    __shared__ unsigned short Ws[64 * 72];

    const int t  = threadIdx.x;
    const int sr = t >> 2, sp = t & 3;

    {
        const float* xsrc = x + ((size_t)blk * 64 + sr) * 64 + sp * 16;
        unsigned o32[8];
#pragma unroll
        for (int u4 = 0; u4 < 4; ++u4) {
            float4 a = ((const float4*)xsrc)[u4];
            o32[u4 * 2 + 0] = pk2bf(a.x, a.y);
            o32[u4 * 2 + 1] = pk2bf(a.z, a.w);
        }
        *(uint4*)&Xs[sr * 72 + sp * 16]     = *(uint4*)&o32[0];
        *(uint4*)&Xs[sr * 72 + sp * 16 + 8] = *(uint4*)&o32[4];
        const float* wsrc = W + (size_t)sr * 64 + sp * 16;
#pragma unroll
        for (int u4 = 0; u4 < 4; ++u4) {
            float4 a = ((const float4*)wsrc)[u4];
            o32[u4 * 2 + 0] = pk2bf(a.x, a.y);
            o32[u4 * 2 + 1] = pk2bf(a.z, a.w);
        }
        *(uint4*)&Ws[sr * 72 + sp * 16]     = *(uint4*)&o32[0];
        *(uint4*)&Ws[sr * 72 + sp * 16 + 8] = *(uint4*)&o32[4];
    }
    __syncthreads();

    const int w    = t >> 6;
    const int lane = t & 63;
    const int l15  = lane & 15;
    const int quad = lane >> 4;

    bf16x8 af0 = *(const bf16x8*)&Xs[(w * 16 + l15) * 72 + quad * 8];
    bf16x8 af1 = *(const bf16x8*)&Xs[(w * 16 + l15) * 72 + 32 + quad * 8];

    f32x4 acc[4];
#pragma unroll
    for (int nt = 0; nt < 4; ++nt) {
        bf16x8 bf0 = *(const bf16x8*)&Ws[(nt * 16 + l15) * 72 + quad * 8];
        bf16x8 bf1 = *(const bf16x8*)&Ws[(nt * 16 + l15) * 72 + 32 + quad * 8];
        f32x4 a = {0, 0, 0, 0};
        a = __builtin_amdgcn_mfma_f32_16x16x32_bf16(af0, bf0, a, 0, 0, 0);
        a = __builtin_amdgcn_mfma_f32_16x16x32_bf16(af1, bf1, a, 0, 0, 0);
        acc[nt] = a;
    }

    const int bsidx = blk * 4 + w;
    const int b = bsidx >> 11, s = bsidx & 2047;
#pragma unroll
    for (int nt = 0; nt < 4; ++nt) {
        const int d = nt * 16 + l15;
        const float bb = bias[d];
#pragma unroll
        for (int r = 0; r < 4; ++r) {
            const int h = quad * 4 + r;
            out[(((size_t)b * HEADS + h) * SEQ + s) * DH + d] =
                f2bf((acc[nt][r] + bb) * oscale);
        }
    }
}

// ---------------------------------------------------------------------------
// Kernel 2 (fused prep): vtrans (bid<1024) | maskpack (<1536) | wcvt (rest)
// ---------------------------------------------------------------------------
__global__ __launch_bounds__(256) void prep_kernel(
    const unsigned short* __restrict__ vh, unsigned short* __restrict__ vt,
    const int* __restrict__ mask, u64* __restrict__ bits,
    const float* __restrict__ Wo, unsigned short* __restrict__ Wob)
{
    __shared__ unsigned short Tt[64 * 72];
    const int bid = blockIdx.x;
    const int t   = threadIdx.x;

    if (bid < 1024) {                     // ---- V transpose ----
        const int st = bid & 31;
        const int bh = bid >> 5;
        const int r = t >> 2, p = t & 3;
        const unsigned short* src = vh + ((size_t)bh * SEQ + st * 64 + r) * DH + p * 16;
        *(uint4*)&Tt[r * 72 + p * 16]     = *(const uint4*)src;
        *(uint4*)&Tt[r * 72 + p * 16 + 8] = *(const uint4*)(src + 8);
        __syncthreads();
        union { unsigned short u[16]; uint4 v[2]; } o;
#pragma unroll
        for (int u = 0; u < 16; ++u) o.u[u] = Tt[(p * 16 + u) * 72 + r];
        unsigned short* dst = vt + ((size_t)bh * DH + r) * SEQ + st * 64 + p * 16;
        *(uint4*)dst       = o.v[0];
        *(uint4*)(dst + 8) = o.v[1];
    } else if (bid < 1536) {              // ---- mask -> bitmask ----
        const int idx = (bid - 1024) * 256 + t;
        const int4* src = (const int4*)(mask + (size_t)idx * 64);
        u64 w = 0;
#pragma unroll
        for (int u = 0; u < 16; ++u) {
            int4 m = src[u];
            u64 nib = (m.x != 0 ? 1ull : 0) | (m.y != 0 ? 2ull : 0) |
                      (m.z != 0 ? 4ull : 0) | (m.w != 0 ? 8ull : 0);
            w |= nib << (u * 4);
        }
        bits[idx] = w;
    } else {                              // ---- Wo fp32 -> bf16 ----
        const int i = ((bid - 1536) * 256 + t) * 8;
        float4 a = ((const float4*)(Wo + i))[0];
        float4 b = ((const float4*)(Wo + i))[1];
        unsigned o32[4] = {pk2bf(a.x, a.y), pk2bf(a.z, a.w),
                           pk2bf(b.x, b.y), pk2bf(b.z, b.w)};
        *(uint4*)(Wob + i) = *(uint4*)o32;
    }
}

// ---------------------------------------------------------------------------
// Kernel 3: MFMA flash attention. Transposed scores (P in registers as the
// K=16 MFMA A-fragment), MFMA row-sums, split-K in block, and register-free
// K/V staging via global_load_lds into XOR-swizzled unpadded LDS tiles:
// element chunk c8 (8 elems) of row r lives at chunk c8^(r&7) -> conflict-free
// reads with zero VGPR staging cost (fixes R7's scratch-spill regression).
// block = 256 (4 waves): waves 0-1 = K half 0 (K-DMA / V-DMA), waves 2-3 =
// half 1. grid = flat 1024 (4 blocks/CU); bh = bid & 31 for XCD locality.
// ---------------------------------------------------------------------------
__global__ __launch_bounds__(256, 4) void attn_kernel(
    const unsigned short* __restrict__ qh, const unsigned short* __restrict__ kh,
    const unsigned short* __restrict__ vt, const u64* __restrict__ mbits,
    unsigned short* __restrict__ ctx)
{
    const int bid = blockIdx.x;
    const int bh  = bid & 31;
    const int q0  = (bid >> 5) * 64;
    const int b   = bh >> 4;

    __shared__ unsigned char smem[32768];   // 2 halves x (K 8K + V 8K); epilogue reuse

    const int t    = threadIdx.x;
    const int hh   = t >> 7;              // K-half (waves 0-1 / 2-3)
    const int w2   = (t >> 6) & 1;        // wave within half: 0 = K-DMA, 1 = V-DMA
    const int lane = t & 63;
    const int l15  = lane & 15;
    const int quad = lane >> 4;

    unsigned short* KtH = (unsigned short*)(smem + hh * 16384);
    unsigned short* VtH = KtH + 4096;

    // DMA source swizzle: LDS slot (row i*8+srow, chunk lane&7) <- global chunk
    // (lane&7)^srow of that row (srow = lane>>3).
    const int srow   = lane >> 3;
    const int schunk = (lane & 7) ^ srow;

    // Q fragments (32 rows per wave, resident for the whole loop)
    bf16x8 qf[2][2];
#pragma unroll
    for (int g = 0; g < 2; ++g) {
        const unsigned short* qb =
            qh + ((size_t)bh * SEQ + q0 + w2 * 32 + g * 16 + l15) * DH + quad * 8;
        qf[g][0] = *(const bf16x8*)qb;
        qf[g][1] = *(const bf16x8*)(qb + 32);
    }

    f32x4 O[2][4];
#pragma unroll
    for (int g = 0; g < 2; ++g)
#pragma unroll
        for (int dt = 0; dt < 4; ++dt) O[g][dt] = f32x4{0, 0, 0, 0};
    f32x4 Osum[2] = {f32x4{0, 0, 0, 0}, f32x4{0, 0, 0, 0}};
    const bf16x4 ones = {(short)0x3F80, (short)0x3F80, (short)0x3F80, (short)0x3F80};

    const unsigned short* kbase = kh + (size_t)bh * SEQ * DH + (size_t)hh * 1024 * DH
                                  + (size_t)srow * DH + schunk * 8;
    const unsigned short* vbase = vt + (size_t)bh * DH * SEQ + hh * 1024
                                  + (size_t)srow * SEQ + schunk * 8;
    const u64* mrow0 = mbits + ((size_t)b * SEQ + q0 + w2 * 32 + l15) * (SEQ / 64) + hh * 16;
    const u64* mrow1 = mrow0 + 16 * (SEQ / 64);

    for (int kt = 0; kt < 16; ++kt) {
        __syncthreads();                  // previous tile's readers done
        if (w2 == 0) {                    // this wave DMAs the K tile (8 KB)
            const unsigned short* g0 = kbase + (size_t)kt * 64 * DH;
#pragma unroll
            for (int i = 0; i < 8; ++i)
                gl_lds16(g0 + (size_t)i * 8 * DH, (unsigned char*)KtH + i * 1024);
        } else {                          // this wave DMAs the V tile (8 KB)
            const unsigned short* g0 = vbase + kt * 64;
#pragma unroll
            for (int i = 0; i < 8; ++i)
                gl_lds16(g0 + (size_t)i * 8 * SEQ, (unsigned char*)VtH + i * 1024);
        }
        const u64 mb0 = mrow0[kt];
        const u64 mb1 = mrow1[kt];
        __syncthreads();                  // drains DMA (vmcnt) + makes tile visible

        // ---- S^T tiles + masked exp2; P stays in registers ----
        bf16x4 p[2][4];
        const int rx = l15 & 7;           // row-swizzle mask for K reads
#pragma unroll
        for (int st = 0; st < 4; ++st) {
            const int r = st * 16 + l15;
            bf16x8 kf0 = *(const bf16x8*)&KtH[r * 64 + ((quad ^ rx)) * 8];
            bf16x8 kf1 = *(const bf16x8*)&KtH[r * 64 + ((quad ^ rx) ^ 4) * 8];
#pragma unroll
            for (int g = 0; g < 2; ++g) {
                f32x4 sa = {0, 0, 0, 0};
                sa = __builtin_amdgcn_mfma_f32_16x16x32_bf16(kf0, qf[g][0], sa, 0, 0, 0);
                sa = __builtin_amdgcn_mfma_f32_16x16x32_bf16(kf1, qf[g][1], sa, 0, 0, 0);
                const unsigned nib = (unsigned)((g ? mb1 : mb0) >> (st * 16 + quad * 4)) & 0xFu;
                float p0 = (nib & 1u) ? exp2f(sa[0]) : 0.f;
                float p1 = (nib & 2u) ? exp2f(sa[1]) : 0.f;
                float p2 = (nib & 4u) ? exp2f(sa[2]) : 0.f;
                float p3 = (nib & 8u) ? exp2f(sa[3]) : 0.f;
                union { unsigned u2[2]; bf16x4 v; } pu;
                pu.u2[0] = pk2bf(p0, p1);
                pu.u2[1] = pk2bf(p2, p3);
                p[g][st] = pu.v;
                Osum[g] = __builtin_amdgcn_mfma_f32_16x16x16bf16_1k(p[g][st], ones, Osum[g], 0, 0, 0);
            }
        }

        // ---- PV: O[g][dt] += P * V (B-frags from swizzled Vt) ----
#pragma unroll
        for (int dt = 0; dt < 4; ++dt) {
            const int d = dt * 16 + l15;
            const int dx = l15 & 7;
#pragma unroll
            for (int st = 0; st < 4; ++st) {
                const int ch = (st * 2 + (quad >> 1)) ^ dx;
                bf16x4 vb = *(const bf16x4*)&VtH[d * 64 + ch * 8 + (quad & 1) * 4];
                O[0][dt] = __builtin_amdgcn_mfma_f32_16x16x16bf16_1k(p[0][st], vb, O[0][dt], 0, 0, 0);
                O[1][dt] = __builtin_amdgcn_mfma_f32_16x16x16bf16_1k(p[1][st], vb, O[1][dt], 0, 0, 0);
            }
        }
    }

    // ---- merge halves through LDS (fixed-max softmax => pure add) ----
    float* Obuf = (float*)smem;           // [64][68] f32
    float* Ls   = ((float*)smem) + 64 * 68;   // [64]

    __syncthreads();                      // all K/V reads complete
    if (hh == 0) {
#pragma unroll
        for (int g = 0; g < 2; ++g) {
#pragma unroll
            for (int dt = 0; dt < 4; ++dt)
#pragma unroll
                for (int r = 0; r < 4; ++r)
                    Obuf[(w2 * 32 + g * 16 + quad * 4 + r) * 68 + dt * 16 + l15] = O[g][dt][r];
            if (l15 == 0) {
#pragma unroll
                for (int r = 0; r < 4; ++r)
                    Ls[w2 * 32 + g * 16 + quad * 4 + r] = Osum[g][r];
            }
        }
    }
    __syncthreads();
    if (hh == 1) {
#pragma unroll
        for (int g = 0; g < 2; ++g) {
            float invr[4];
#pragma unroll
            for (int r = 0; r < 4; ++r) {
                const int row = w2 * 32 + g * 16 + quad * 4 + r;
                invr[r] = 1.0f / (Osum[g][r] + Ls[row]);
            }
#pragma unroll
            for (int r = 0; r < 4; ++r) {
                const int row = w2 * 32 + g * 16 + quad * 4 + r;
                unsigned short* dst = ctx + ((size_t)bh * SEQ + q0 + row) * DH + l15;
#pragma unroll
                for (int dt = 0; dt < 4; ++dt) {
                    const float val = O[g][dt][r] + Obuf[row * 68 + dt * 16 + l15];
                    dst[dt * 16] = f2bf(val * invr[r]);
                }
            }
        }
    }
}

// ---------------------------------------------------------------------------
// Kernel 4: output projection via MFMA (verified R3/R5/R6).
// ---------------------------------------------------------------------------
__global__ __launch_bounds__(256) void outproj_mfma(
    const unsigned short* __restrict__ ctx, const unsigned short* __restrict__ Wob,
    const float* __restrict__ bo, float* __restrict__ out)
{
    const int n0 = blockIdx.x * 64;
    const int m0 = blockIdx.y * 64;
    const int b  = m0 / SEQ;
    const int s0 = m0 % SEQ;

    __shared__ unsigned short At[64 * 72];
    __shared__ unsigned short Wt[64 * 72];

    const int t    = threadIdx.x;
    const int w    = t >> 6;
    const int lane = t & 63;
    const int l15  = lane & 15;
    const int quad = lane >> 4;
    const int sr = t >> 2, sp = t & 3;

    f32x4 acc[4] = {f32x4{0,0,0,0}, f32x4{0,0,0,0}, f32x4{0,0,0,0}, f32x4{0,0,0,0}};

    for (int kt = 0; kt < HEADS; ++kt) {
        __syncthreads();
        {
            const unsigned short* as =
                ctx + (((size_t)b * HEADS + kt) * SEQ + s0 + sr) * DH + sp * 16;
            *(uint4*)&At[sr * 72 + sp * 16]     = *(const uint4*)as;
            *(uint4*)&At[sr * 72 + sp * 16 + 8] = *(const uint4*)(as + 8);
            const unsigned short* wsrc =
                Wob + (size_t)(n0 + sr) * EMBED + kt * 64 + sp * 16;
            *(uint4*)&Wt[sr * 72 + sp * 16]     = *(const uint4*)wsrc;
            *(uint4*)&Wt[sr * 72 + sp * 16 + 8] = *(const uint4*)(wsrc + 8);
        }
        __syncthreads();

        bf16x8 bf0 = *(const bf16x8*)&Wt[(w * 16 + l15) * 72 + quad * 8];
        bf16x8 bf1 = *(const bf16x8*)&Wt[(w * 16 + l15) * 72 + 32 + quad * 8];
#pragma unroll
        for (int mt = 0; mt < 4; ++mt) {
            bf16x8 af0 = *(const bf16x8*)&At[(mt * 16 + l15) * 72 + quad * 8];
            bf16x8 af1 = *(const bf16x8*)&At[(mt * 16 + l15) * 72 + 32 + quad * 8];
            acc[mt] = __builtin_amdgcn_mfma_f32_16x16x32_bf16(af0, bf0, acc[mt], 0, 0, 0);
            acc[mt] = __builtin_amdgcn_mfma_f32_16x16x32_bf16(af1, bf1, acc[mt], 0, 0, 0);
        }
    }

    const float bv = bo[n0 + w * 16 + l15];
#pragma unroll
    for (int mt = 0; mt < 4; ++mt) {
#pragma unroll
        for (int r = 0; r < 4; ++r) {
            out[(size_t)(m0 + mt * 16 + quad * 4 + r) * EMBED + n0 + w * 16 + l15] =
                acc[mt][r] + bv;
        }
    }
}

// ---------------------------------------------------------------------------
extern "C" void kernel_launch(void* const* d_in, const int* in_sizes, int n_in,
                              void* d_out, int out_size, void* d_ws, size_t ws_size,
                              hipStream_t stream) {
    const float* k    = (const float*)d_in[0];
    const float* q    = (const float*)d_in[1];
    const float* v    = (const float*)d_in[2];
    const int*   mask = (const int*)  d_in[3];
    const float* Wk   = (const float*)d_in[4];
    const float* bk   = (const float*)d_in[5];
    const float* Wq   = (const float*)d_in[6];
    const float* bq   = (const float*)d_in[7];
    const float* Wv   = (const float*)d_in[8];
    const float* bv   = (const float*)d_in[9];
    const float* Wo   = (const float*)d_in[10];
    const float* bo   = (const float*)d_in[11];
    float* out = (float*)d_out;

    const size_t TEN = (size_t)BATCH * HEADS * SEQ * DH;   // 4,194,304 elems
    unsigned short* qh_bf = (unsigned short*)d_ws;         // 8 MB
    unsigned short* kh_bf = qh_bf + TEN;                   // 8 MB
    unsigned short* vh_bf = kh_bf + TEN;                   // 8 MB
    unsigned short* vt_bf = vh_bf + TEN;                   // 8 MB
    unsigned short* ctxb  = vt_bf + TEN;                   // 8 MB
    unsigned short* Wob   = ctxb + TEN;                    // 2 MB
    u64*            mbits = (u64*)(Wob + EMBED * EMBED);   // 1 MB  (43 MB total)

    proj_mfma<<<dim3(BATCH * SEQ * HEADS / 64, 3), 256, 0, stream>>>(
        q, k, v, Wq, bq, Wk, bk, Wv, bv, qh_bf, kh_bf, vh_bf);
    prep_kernel<<<dim3(2048), 256, 0, stream>>>(
        vh_bf, vt_bf, mask, mbits, Wo, Wob);
    attn_kernel<<<dim3((SEQ / 64) * BATCH * HEADS), 256, 0, stream>>>(
        qh_bf, kh_bf, vt_bf, mbits, ctxb);
    outproj_mfma<<<dim3(EMBED / 64, BATCH * SEQ / 64), 256, 0, stream>>>(
        ctxb, Wob, bo, out);
}

// Round 9
// 245.403 us; speedup vs baseline: 1.5466x; 1.0167x over previous
//
#include <hip/hip_runtime.h>
#include <hip/hip_bf16.h>
#include <math.h>

#define EMBED 1024
#define HEADS 16
#define DH    64
#define BATCH 2
#define SEQ   2048

typedef __attribute__((ext_vector_type(8))) short bf16x8;
typedef __attribute__((ext_vector_type(4))) short bf16x4;
typedef __attribute__((ext_vector_type(4))) float f32x4;
typedef unsigned long long u64;

#define QSCALE 0.1803368801111244f   // 0.125 * log2(e): exp(s/8) == exp2(s*QSCALE)

static __device__ __forceinline__ unsigned short f2bf(float x) {
    unsigned u = __builtin_bit_cast(unsigned, x);
    return (unsigned short)((u + 0x7fffu + ((u >> 16) & 1u)) >> 16);
}
static __device__ __forceinline__ unsigned pk2bf(float a, float b) {
    union { __hip_bfloat162 h2; unsigned u; } c;
    c.h2 = __float22bfloat162_rn(make_float2(a, b));
    return c.u;
}
// async global->LDS DMA, 16 B per lane; LDS dest = wave-uniform base + lane*16
static __device__ __forceinline__ void gl_lds16(const void* g, void* l) {
    __builtin_amdgcn_global_load_lds(
        (const __attribute__((address_space(1))) void*)g,
        (__attribute__((address_space(3))) void*)l, 16, 0, 0);
}

// ---------------------------------------------------------------------------
// Kernel 1: QKV projection via MFMA (verified R5-R8). X viewed as [B*S*H][64];
// Y = X W^T + b, bf16 out to [B,H,S,DH]. Q pre-scaled by QSCALE (exp2 softmax).
// grid = (1024, 3), block = 256.
// ---------------------------------------------------------------------------
__global__ __launch_bounds__(256) void proj_mfma(
    const float* __restrict__ q, const float* __restrict__ k, const float* __restrict__ v,
    const float* __restrict__ Wq, const float* __restrict__ bq,
    const float* __restrict__ Wk, const float* __restrict__ bk,
    const float* __restrict__ Wv, const float* __restrict__ bv,
    unsigned short* __restrict__ qh, unsigned short* __restrict__ kh,
    unsigned short* __restrict__ vh)
{
    const int blk = blockIdx.x;
    const int which = blockIdx.y;
    const float* x; const float* W; const float* bias; unsigned short* out;
    if (which == 0)      { x = q; W = Wq; bias = bq; out = qh; }
    else if (which == 1) { x = k; W = Wk; bias = bk; out = kh; }
    else                 { x = v; W = Wv; bias = bv; out = vh; }
    const float oscale = (which == 0) ? QSCALE : 1.0f;

    __shared__ unsigned short Xs[64 * 72];
    __shared__ unsigned short Ws[64 * 72];

    const int t  = threadIdx.x;
    const int sr = t >> 2, sp = t & 3;

    {
        const float* xsrc = x + ((size_t)blk * 64 + sr) * 64 + sp * 16;
        unsigned o32[8];
#pragma unroll
        for (int u4 = 0; u4 < 4; ++u4) {
            float4 a = ((const float4*)xsrc)[u4];
            o32[u4 * 2 + 0] = pk2bf(a.x, a.y);
            o32[u4 * 2 + 1] = pk2bf(a.z, a.w);
        }
        *(uint4*)&Xs[sr * 72 + sp * 16]     = *(uint4*)&o32[0];
        *(uint4*)&Xs[sr * 72 + sp * 16 + 8] = *(uint4*)&o32[4];
        const float* wsrc = W + (size_t)sr * 64 + sp * 16;
#pragma unroll
        for (int u4 = 0; u4 < 4; ++u4) {
            float4 a = ((const float4*)wsrc)[u4];
            o32[u4 * 2 + 0] = pk2bf(a.x, a.y);
            o32[u4 * 2 + 1] = pk2bf(a.z, a.w);
        }
        *(uint4*)&Ws[sr * 72 + sp * 16]     = *(uint4*)&o32[0];
        *(uint4*)&Ws[sr * 72 + sp * 16 + 8] = *(uint4*)&o32[4];
    }
    __syncthreads();

    const int w    = t >> 6;
    const int lane = t & 63;
    const int l15  = lane & 15;
    const int quad = lane >> 4;

    bf16x8 af0 = *(const bf16x8*)&Xs[(w * 16 + l15) * 72 + quad * 8];
    bf16x8 af1 = *(const bf16x8*)&Xs[(w * 16 + l15) * 72 + 32 + quad * 8];

    f32x4 acc[4];
#pragma unroll
    for (int nt = 0; nt < 4; ++nt) {
        bf16x8 bf0 = *(const bf16x8*)&Ws[(nt * 16 + l15) * 72 + quad * 8];
        bf16x8 bf1 = *(const bf16x8*)&Ws[(nt * 16 + l15) * 72 + 32 + quad * 8];
        f32x4 a = {0, 0, 0, 0};
        a = __builtin_amdgcn_mfma_f32_16x16x32_bf16(af0, bf0, a, 0, 0, 0);
        a = __builtin_amdgcn_mfma_f32_16x16x32_bf16(af1, bf1, a, 0, 0, 0);
        acc[nt] = a;
    }

    const int bsidx = blk * 4 + w;
    const int b = bsidx >> 11, s = bsidx & 2047;
#pragma unroll
    for (int nt = 0; nt < 4; ++nt) {
        const int d = nt * 16 + l15;
        const float bb = bias[d];
#pragma unroll
        for (int r = 0; r < 4; ++r) {
            const int h = quad * 4 + r;
            out[(((size_t)b * HEADS + h) * SEQ + s) * DH + d] =
                f2bf((acc[nt][r] + bb) * oscale);
        }
    }
}

// ---------------------------------------------------------------------------
// Kernel 2 (fused prep): vtrans (bid<1024) | maskpack (<1536) | wcvt (rest)
// ---------------------------------------------------------------------------
__global__ __launch_bounds__(256) void prep_kernel(
    const unsigned short* __restrict__ vh, unsigned short* __restrict__ vt,
    const int* __restrict__ mask, u64* __restrict__ bits,
    const float* __restrict__ Wo, unsigned short* __restrict__ Wob)
{
    __shared__ unsigned short Tt[64 * 72];
    const int bid = blockIdx.x;
    const int t   = threadIdx.x;

    if (bid < 1024) {                     // ---- V transpose ----
        const int st = bid & 31;
        const int bh = bid >> 5;
        const int r = t >> 2, p = t & 3;
        const unsigned short* src = vh + ((size_t)bh * SEQ + st * 64 + r) * DH + p * 16;
        *(uint4*)&Tt[r * 72 + p * 16]     = *(const uint4*)src;
        *(uint4*)&Tt[r * 72 + p * 16 + 8] = *(const uint4*)(src + 8);
        __syncthreads();
        union { unsigned short u[16]; uint4 v[2]; } o;
#pragma unroll
        for (int u = 0; u < 16; ++u) o.u[u] = Tt[(p * 16 + u) * 72 + r];
        unsigned short* dst = vt + ((size_t)bh * DH + r) * SEQ + st * 64 + p * 16;
        *(uint4*)dst       = o.v[0];
        *(uint4*)(dst + 8) = o.v[1];
    } else if (bid < 1536) {              // ---- mask -> bitmask ----
        const int idx = (bid - 1024) * 256 + t;
        const int4* src = (const int4*)(mask + (size_t)idx * 64);
        u64 w = 0;
#pragma unroll
        for (int u = 0; u < 16; ++u) {
            int4 m = src[u];
            u64 nib = (m.x != 0 ? 1ull : 0) | (m.y != 0 ? 2ull : 0) |
                      (m.z != 0 ? 4ull : 0) | (m.w != 0 ? 8ull : 0);
            w |= nib << (u * 4);
        }
        bits[idx] = w;
    } else {                              // ---- Wo fp32 -> bf16 ----
        const int i = ((bid - 1536) * 256 + t) * 8;
        float4 a = ((const float4*)(Wo + i))[0];
        float4 b = ((const float4*)(Wo + i))[1];
        unsigned o32[4] = {pk2bf(a.x, a.y), pk2bf(a.z, a.w),
                           pk2bf(b.x, b.y), pk2bf(b.z, b.w)};
        *(uint4*)(Wob + i) = *(uint4*)o32;
    }
}

// ---------------------------------------------------------------------------
// Kernel 3: MFMA flash attention, double-buffered DMA K-loop.
// Transposed scores (P in registers as K=16 A-frag), MFMA row-sums, split-K
// in block (waves 0-1 = half 0, 2-3 = half 1). Each iteration issues
// global_load_lds for tile kt+1 into buf^1, computes tile kt from buf, then
// barriers: the vmcnt(0) drain lands after a full compute phase -> DMA hidden
// (fixes the R6/R8 barrier-drain plateau). LDS = 2 bufs x 32 KB = 64 KB.
// grid = flat 1024; bh = bid & 31 for XCD-local K/V reuse.
// ---------------------------------------------------------------------------
__global__ __launch_bounds__(256, 2) void attn_kernel(
    const unsigned short* __restrict__ qh, const unsigned short* __restrict__ kh,
    const unsigned short* __restrict__ vt, const u64* __restrict__ mbits,
    unsigned short* __restrict__ ctx)
{
    const int bid = blockIdx.x;
    const int bh  = bid & 31;
    const int q0  = (bid >> 5) * 64;
    const int b   = bh >> 4;

    __shared__ unsigned char smem[65536];   // buf(32K) x2: [half0 K8K|V8K|half1 K8K|V8K]

    const int t    = threadIdx.x;
    const int hh   = t >> 7;              // K-half (waves 0-1 / 2-3)
    const int w2   = (t >> 6) & 1;        // wave within half: 0 = K-DMA, 1 = V-DMA
    const int lane = t & 63;
    const int l15  = lane & 15;
    const int quad = lane >> 4;

    // DMA source swizzle: LDS slot (row i*8+srow, chunk lane&7) <- global chunk
    // (lane&7)^srow of that row.
    const int srow   = lane >> 3;
    const int schunk = (lane & 7) ^ srow;

    // Q fragments (32 rows per wave, resident for the whole loop)
    bf16x8 qf[2][2];
#pragma unroll
    for (int g = 0; g < 2; ++g) {
        const unsigned short* qb =
            qh + ((size_t)bh * SEQ + q0 + w2 * 32 + g * 16 + l15) * DH + quad * 8;
        qf[g][0] = *(const bf16x8*)qb;
        qf[g][1] = *(const bf16x8*)(qb + 32);
    }

    f32x4 O[2][4];
#pragma unroll
    for (int g = 0; g < 2; ++g)
#pragma unroll
        for (int dt = 0; dt < 4; ++dt) O[g][dt] = f32x4{0, 0, 0, 0};
    f32x4 Osum[2] = {f32x4{0, 0, 0, 0}, f32x4{0, 0, 0, 0}};
    const bf16x4 ones = {(short)0x3F80, (short)0x3F80, (short)0x3F80, (short)0x3F80};

    const unsigned short* kbase = kh + (size_t)bh * SEQ * DH + (size_t)hh * 1024 * DH
                                  + (size_t)srow * DH + schunk * 8;
    const unsigned short* vbase = vt + (size_t)bh * DH * SEQ + hh * 1024
                                  + (size_t)srow * SEQ + schunk * 8;
    const u64* mrow0 = mbits + ((size_t)b * SEQ + q0 + w2 * 32 + l15) * (SEQ / 64) + hh * 16;
    const u64* mrow1 = mrow0 + 16 * (SEQ / 64);

    // issue DMA for tile 0 into buf 0; prefetch mask words for tile 0
    if (w2 == 0) {
        unsigned char* Kd = smem + hh * 16384;
#pragma unroll
        for (int i = 0; i < 8; ++i)
            gl_lds16(kbase + (size_t)i * 8 * DH, Kd + i * 1024);
    } else {
        unsigned char* Vd = smem + hh * 16384 + 8192;
#pragma unroll
        for (int i = 0; i < 8; ++i)
            gl_lds16(vbase + (size_t)i * 8 * SEQ, Vd + i * 1024);
    }
    u64 pm0 = mrow0[0], pm1 = mrow1[0];
    __syncthreads();                      // drains DMA(0)

    for (int kt = 0; kt < 16; ++kt) {
        // ---- issue DMA for tile kt+1 into the other buffer ----
        if (kt < 15) {
            const int bn = (kt + 1) & 1;
            if (w2 == 0) {
                unsigned char* Kd = smem + bn * 32768 + hh * 16384;
                const unsigned short* g0 = kbase + (size_t)(kt + 1) * 64 * DH;
#pragma unroll
                for (int i = 0; i < 8; ++i)
                    gl_lds16(g0 + (size_t)i * 8 * DH, Kd + i * 1024);
            } else {
                unsigned char* Vd = smem + bn * 32768 + hh * 16384 + 8192;
                const unsigned short* g0 = vbase + (kt + 1) * 64;
#pragma unroll
                for (int i = 0; i < 8; ++i)
                    gl_lds16(g0 + (size_t)i * 8 * SEQ, Vd + i * 1024);
            }
        }
        const u64 mb0 = pm0, mb1 = pm1;
        if (kt < 15) { pm0 = mrow0[kt + 1]; pm1 = mrow1[kt + 1]; }

        const unsigned short* KtH = (const unsigned short*)(smem + (kt & 1) * 32768 + hh * 16384);
        const unsigned short* VtH = KtH + 4096;

        // ---- S^T tiles + masked exp2; P stays in registers ----
        bf16x4 p[2][4];
        const int rx = l15 & 7;
#pragma unroll
        for (int st = 0; st < 4; ++st) {
            const int r = st * 16 + l15;
            bf16x8 kf0 = *(const bf16x8*)&KtH[r * 64 + ((quad ^ rx)) * 8];
            bf16x8 kf1 = *(const bf16x8*)&KtH[r * 64 + ((quad ^ rx) ^ 4) * 8];
#pragma unroll
            for (int g = 0; g < 2; ++g) {
                f32x4 sa = {0, 0, 0, 0};
                sa = __builtin_amdgcn_mfma_f32_16x16x32_bf16(kf0, qf[g][0], sa, 0, 0, 0);
                sa = __builtin_amdgcn_mfma_f32_16x16x32_bf16(kf1, qf[g][1], sa, 0, 0, 0);
                const unsigned nib = (unsigned)((g ? mb1 : mb0) >> (st * 16 + quad * 4)) & 0xFu;
                float p0 = (nib & 1u) ? exp2f(sa[0]) : 0.f;
                float p1 = (nib & 2u) ? exp2f(sa[1]) : 0.f;
                float p2 = (nib & 4u) ? exp2f(sa[2]) : 0.f;
                float p3 = (nib & 8u) ? exp2f(sa[3]) : 0.f;
                union { unsigned u2[2]; bf16x4 v; } pu;
                pu.u2[0] = pk2bf(p0, p1);
                pu.u2[1] = pk2bf(p2, p3);
                p[g][st] = pu.v;
                Osum[g] = __builtin_amdgcn_mfma_f32_16x16x16bf16_1k(p[g][st], ones, Osum[g], 0, 0, 0);
            }
        }

        // ---- PV: O[g][dt] += P * V (B-frags from swizzled Vt) ----
#pragma unroll
        for (int dt = 0; dt < 4; ++dt) {
            const int d = dt * 16 + l15;
            const int dx = l15 & 7;
#pragma unroll
            for (int st = 0; st < 4; ++st) {
                const int ch = (st * 2 + (quad >> 1)) ^ dx;
                bf16x4 vb = *(const bf16x4*)&VtH[d * 64 + ch * 8 + (quad & 1) * 4];
                O[0][dt] = __builtin_amdgcn_mfma_f32_16x16x16bf16_1k(p[0][st], vb, O[0][dt], 0, 0, 0);
                O[1][dt] = __builtin_amdgcn_mfma_f32_16x16x16bf16_1k(p[1][st], vb, O[1][dt], 0, 0, 0);
            }
        }
        __syncthreads();   // readers done with buf(kt); drains DMA(kt+1) post-compute
    }

    // ---- merge halves through LDS (fixed-max softmax => pure add) ----
    float* Obuf = (float*)smem;           // [64][68] f32
    float* Ls   = ((float*)smem) + 64 * 68;   // [64]

    if (hh == 0) {
#pragma unroll
        for (int g = 0; g < 2; ++g) {
#pragma unroll
            for (int dt = 0; dt < 4; ++dt)
#pragma unroll
                for (int r = 0; r < 4; ++r)
                    Obuf[(w2 * 32 + g * 16 + quad * 4 + r) * 68 + dt * 16 + l15] = O[g][dt][r];
            if (l15 == 0) {
#pragma unroll
                for (int r = 0; r < 4; ++r)
                    Ls[w2 * 32 + g * 16 + quad * 4 + r] = Osum[g][r];
            }
        }
    }
    __syncthreads();
    if (hh == 1) {
#pragma unroll
        for (int g = 0; g < 2; ++g) {
            float invr[4];
#pragma unroll
            for (int r = 0; r < 4; ++r) {
                const int row = w2 * 32 + g * 16 + quad * 4 + r;
                invr[r] = 1.0f / (Osum[g][r] + Ls[row]);
            }
#pragma unroll
            for (int r = 0; r < 4; ++r) {
                const int row = w2 * 32 + g * 16 + quad * 4 + r;
                unsigned short* dst = ctx + ((size_t)bh * SEQ + q0 + row) * DH + l15;
#pragma unroll
                for (int dt = 0; dt < 4; ++dt) {
                    const float val = O[g][dt][r] + Obuf[row * 68 + dt * 16 + l15];
                    dst[dt * 16] = f2bf(val * invr[r]);
                }
            }
        }
    }
}

// ---------------------------------------------------------------------------
// Kernel 4: output projection via MFMA, DMA-staged + double-buffered.
// out[m,n] = sum_k ctx[m,k]*Wo[n,k] + bo[n]; 64x64 C-tile, BK = 64 = one head.
// A/W tiles staged with global_load_lds into XOR-swizzled unpadded LDS
// (same verified swizzle as attn). LDS = 2 bufs x 16 KB = 32 KB.
// grid = (16, 64), block = 256.
// ---------------------------------------------------------------------------
__global__ __launch_bounds__(256, 4) void outproj_mfma(
    const unsigned short* __restrict__ ctx, const unsigned short* __restrict__ Wob,
    const float* __restrict__ bo, float* __restrict__ out)
{
    const int n0 = blockIdx.x * 64;
    const int m0 = blockIdx.y * 64;
    const int b  = m0 / SEQ;
    const int s0 = m0 % SEQ;

    __shared__ unsigned char smem[32768];   // buf(16K) x2: [A 8K | W 8K]

    const int t    = threadIdx.x;
    const int w    = t >> 6;
    const int lane = t & 63;
    const int l15  = lane & 15;
    const int quad = lane >> 4;
    const int srow   = lane >> 3;
    const int schunk = (lane & 7) ^ srow;

    // A row (kt,i): ctx[((b*16+kt)*2048 + s0 + i*8 + srow)*64 + schunk*8]
    const unsigned short* abase = ctx + ((size_t)b * HEADS * SEQ + s0 + srow) * DH + schunk * 8;
    // W row (kt,i): Wob[(n0 + i*8 + srow)*1024 + kt*64 + schunk*8]
    const unsigned short* wbase = Wob + (size_t)(n0 + srow) * EMBED + schunk * 8;

    f32x4 acc[4] = {f32x4{0,0,0,0}, f32x4{0,0,0,0}, f32x4{0,0,0,0}, f32x4{0,0,0,0}};

    // issue DMA for kt = 0 into buf 0 (wave w covers 4 of the 16 row-block issues)
    {
        unsigned char* Ab = smem;
        unsigned char* Wb = smem + 8192;
#pragma unroll
        for (int j = 0; j < 4; ++j) {
            const int idx = w * 4 + j;
            if (idx < 8)
                gl_lds16(abase + (size_t)idx * 8 * DH, Ab + idx * 1024);
            else
                gl_lds16(wbase + (size_t)(idx - 8) * 8 * EMBED, Wb + (idx - 8) * 1024);
        }
    }
    __syncthreads();                      // drains DMA(0)

    for (int kt = 0; kt < 16; ++kt) {
        if (kt < 15) {
            const int ktn = kt + 1;
            unsigned char* Ab = smem + (ktn & 1) * 16384;
            unsigned char* Wb = Ab + 8192;
#pragma unroll
            for (int j = 0; j < 4; ++j) {
                const int idx = w * 4 + j;
                if (idx < 8)
                    gl_lds16(abase + (size_t)ktn * SEQ * DH + (size_t)idx * 8 * DH,
                             Ab + idx * 1024);
                else
                    gl_lds16(wbase + (size_t)(idx - 8) * 8 * EMBED + ktn * 64,
                             Wb + (idx - 8) * 1024);
            }
        }

        const unsigned short* At = (const unsigned short*)(smem + (kt & 1) * 16384);
        const unsigned short* Wt = At + 4096;
        const int rx = l15 & 7;
        const int c0 = ((quad ^ rx)) * 8;

        bf16x8 bf0 = *(const bf16x8*)&Wt[(w * 16 + l15) * 64 + c0];
        bf16x8 bf1 = *(const bf16x8*)&Wt[(w * 16 + l15) * 64 + (c0 ^ 32)];
#pragma unroll
        for (int mt = 0; mt < 4; ++mt) {
            bf16x8 af0 = *(const bf16x8*)&At[(mt * 16 + l15) * 64 + c0];
            bf16x8 af1 = *(const bf16x8*)&At[(mt * 16 + l15) * 64 + (c0 ^ 32)];
            acc[mt] = __builtin_amdgcn_mfma_f32_16x16x32_bf16(af0, bf0, acc[mt], 0, 0, 0);
            acc[mt] = __builtin_amdgcn_mfma_f32_16x16x32_bf16(af1, bf1, acc[mt], 0, 0, 0);
        }
        __syncthreads();   // readers done with buf(kt); drains DMA(kt+1) post-compute
    }

    const float bv = bo[n0 + w * 16 + l15];
#pragma unroll
    for (int mt = 0; mt < 4; ++mt) {
#pragma unroll
        for (int r = 0; r < 4; ++r) {
            out[(size_t)(m0 + mt * 16 + quad * 4 + r) * EMBED + n0 + w * 16 + l15] =
                acc[mt][r] + bv;
        }
    }
}

// ---------------------------------------------------------------------------
extern "C" void kernel_launch(void* const* d_in, const int* in_sizes, int n_in,
                              void* d_out, int out_size, void* d_ws, size_t ws_size,
                              hipStream_t stream) {
    const float* k    = (const float*)d_in[0];
    const float* q    = (const float*)d_in[1];
    const float* v    = (const float*)d_in[2];
    const int*   mask = (const int*)  d_in[3];
    const float* Wk   = (const float*)d_in[4];
    const float* bk   = (const float*)d_in[5];
    const float* Wq   = (const float*)d_in[6];
    const float* bq   = (const float*)d_in[7];
    const float* Wv   = (const float*)d_in[8];
    const float* bv   = (const float*)d_in[9];
    const float* Wo   = (const float*)d_in[10];
    const float* bo   = (const float*)d_in[11];
    float* out = (float*)d_out;

    const size_t TEN = (size_t)BATCH * HEADS * SEQ * DH;   // 4,194,304 elems
    unsigned short* qh_bf = (unsigned short*)d_ws;         // 8 MB
    unsigned short* kh_bf = qh_bf + TEN;                   // 8 MB
    unsigned short* vh_bf = kh_bf + TEN;                   // 8 MB
    unsigned short* vt_bf = vh_bf + TEN;                   // 8 MB
    unsigned short* ctxb  = vt_bf + TEN;                   // 8 MB
    unsigned short* Wob   = ctxb + TEN;                    // 2 MB
    u64*            mbits = (u64*)(Wob + EMBED * EMBED);   // 1 MB  (43 MB total)

    proj_mfma<<<dim3(BATCH * SEQ * HEADS / 64, 3), 256, 0, stream>>>(
        q, k, v, Wq, bq, Wk, bk, Wv, bv, qh_bf, kh_bf, vh_bf);
    prep_kernel<<<dim3(2048), 256, 0, stream>>>(
        vh_bf, vt_bf, mask, mbits, Wo, Wob);
    attn_kernel<<<dim3((SEQ / 64) * BATCH * HEADS), 256, 0, stream>>>(
        qh_bf, kh_bf, vt_bf, mbits, ctxb);
    outproj_mfma<<<dim3(EMBED / 64, BATCH * SEQ / 64), 256, 0, stream>>>(
        ctxb, Wob, bo, out);
}